// Round 4
// baseline (830.202 us; speedup 1.0000x reference)
//
#include <hip/hip_runtime.h>
#include <hip/hip_fp16.h>

#define NEG_SLOPE 0.2f
#define BKN 128                 // nodes per bucket (pow2)
#define MAXNB 1024              // supports n <= 131072

// ---------------------------------------------------------------------------
// Fused GEMM + attention-logit kernel.
//   H[n, BN]   = fp16( X[n, 128] @ W[128, BN] )     (message payload, fp16)
//   As[n, hd]  = sum_c Hf32[n, hd*C+c] * atts[...]  (logits from fp32 accs)
//   Ad[n, hd]  = sum_c Hf32[n, hd*C+c] * attd[...]
// ---------------------------------------------------------------------------
template<int BN, int BM, int C>
__global__ __launch_bounds__(256) void gemm_att(
    const float* __restrict__ X, const float* __restrict__ W,
    const float* __restrict__ atts, const float* __restrict__ attd,
    __half* __restrict__ H, float* __restrict__ As, float* __restrict__ Ad,
    int n)
{
    constexpr int K  = 128;
    constexpr int CG = BN / 4;          // column groups of 4
    constexpr int RW = C / 4;           // shuffle-reduce width (lanes per head)
    constexpr int HEADS = BN / C;

    __shared__ float Wl[K * BN];
    __shared__ float Xl[K * BM];

    const int t = threadIdx.x;
    for (int i = t; i < K * BN / 4; i += 256)
        ((float4*)Wl)[i] = ((const float4*)W)[i];

    const int cg   = t % CG;
    const int rg   = t / CG;
    const int col0 = cg * 4;
    const int head = col0 / C;
    const float s0 = atts[col0], s1 = atts[col0+1], s2 = atts[col0+2], s3 = atts[col0+3];
    const float d0 = attd[col0], d1 = attd[col0+1], d2 = attd[col0+2], d3 = attd[col0+3];

    const int numTiles = (n + BM - 1) / BM;
    for (int tile = blockIdx.x; tile < numTiles; tile += gridDim.x) {
        const int row0 = tile * BM;
        __syncthreads();
        for (int i = t; i < BM * (K / 4); i += 256) {
            int r = i % BM, k4 = i / BM;
            int row = row0 + r;
            float4 v = make_float4(0.f, 0.f, 0.f, 0.f);
            if (row < n) v = ((const float4*)(X + (size_t)row * K))[k4];
            Xl[(k4*4+0)*BM + r] = v.x;
            Xl[(k4*4+1)*BM + r] = v.y;
            Xl[(k4*4+2)*BM + r] = v.z;
            Xl[(k4*4+3)*BM + r] = v.w;
        }
        __syncthreads();

        float acc[4][4];
        #pragma unroll
        for (int a = 0; a < 4; ++a)
            #pragma unroll
            for (int b = 0; b < 4; ++b) acc[a][b] = 0.f;

        #pragma unroll 8
        for (int k = 0; k < K; ++k) {
            float4 a = ((const float4*)(Xl + k * BM))[rg];
            float4 b = ((const float4*)(Wl + k * BN))[cg];
            acc[0][0] += a.x*b.x; acc[0][1] += a.x*b.y; acc[0][2] += a.x*b.z; acc[0][3] += a.x*b.w;
            acc[1][0] += a.y*b.x; acc[1][1] += a.y*b.y; acc[1][2] += a.y*b.z; acc[1][3] += a.y*b.w;
            acc[2][0] += a.z*b.x; acc[2][1] += a.z*b.y; acc[2][2] += a.z*b.z; acc[2][3] += a.z*b.w;
            acc[3][0] += a.w*b.x; acc[3][1] += a.w*b.y; acc[3][2] += a.w*b.z; acc[3][3] += a.w*b.w;
        }

        #pragma unroll
        for (int ri = 0; ri < 4; ++ri) {
            int row = row0 + rg * 4 + ri;
            bool ok = row < n;
            if (ok) {
                __half2 p0 = __floats2half2_rn(acc[ri][0], acc[ri][1]);
                __half2 p1 = __floats2half2_rn(acc[ri][2], acc[ri][3]);
                uint2 u;
                u.x = *(unsigned*)&p0;
                u.y = *(unsigned*)&p1;
                ((uint2*)(H + (size_t)row * BN))[cg] = u;   // 8B packed store
            }
            float ps = acc[ri][0]*s0 + acc[ri][1]*s1 + acc[ri][2]*s2 + acc[ri][3]*s3;
            float pd = acc[ri][0]*d0 + acc[ri][1]*d1 + acc[ri][2]*d2 + acc[ri][3]*d3;
            #pragma unroll
            for (int off = RW / 2; off > 0; off >>= 1) {
                ps += __shfl_down(ps, off, RW);
                pd += __shfl_down(pd, off, RW);
            }
            if (ok && (cg % RW) == 0) {
                As[(size_t)row * HEADS + head] = ps;
                Ad[(size_t)row * HEADS + head] = pd;
            }
        }
    }
}

// ---------------------------------------------------------------------------
// CSR build, bucketed 2-pass counting sort. Bucket = dst >> 7 (128 nodes).
//  1) bucket_hist : per-block LDS histogram -> global bcount
//  2) bucket_scan : 1 block scans bcount -> bbase (bases), bcur (cursors)
//  3) pass1       : edge -> tmp[bucket region], packed (src<<7)|(dst&127)
//  4) pass2       : per-bucket LDS counting sort -> esrc + final offs[]
// offs[v] == end(v); beg(v) = (v ? offs[v-1] : 0).
// ---------------------------------------------------------------------------
__global__ __launch_bounds__(256) void bucket_hist(
    const int* __restrict__ ei, int E, int Etot, int NB, int* __restrict__ bcount)
{
    __shared__ int h[MAXNB];
    for (int i = threadIdx.x; i < NB; i += 256) h[i] = 0;
    __syncthreads();
    for (int e = blockIdx.x * 256 + threadIdx.x; e < Etot; e += gridDim.x * 256) {
        int dst = (e < E) ? ei[E + e] : (e - E);
        atomicAdd(&h[dst >> 7], 1);
    }
    __syncthreads();
    for (int i = threadIdx.x; i < NB; i += 256)
        if (h[i]) atomicAdd(&bcount[i], h[i]);
}

__global__ __launch_bounds__(256) void bucket_scan(
    const int* __restrict__ bcount, int NB, int Etot,
    int* __restrict__ bbase, int* __restrict__ bcur)
{
    __shared__ int s[256];
    int t = threadIdx.x;
    int i0 = t * 4;
    int v0 = (i0     < NB) ? bcount[i0]     : 0;
    int v1 = (i0 + 1 < NB) ? bcount[i0 + 1] : 0;
    int v2 = (i0 + 2 < NB) ? bcount[i0 + 2] : 0;
    int v3 = (i0 + 3 < NB) ? bcount[i0 + 3] : 0;
    int tsum = v0 + v1 + v2 + v3;
    s[t] = tsum;
    __syncthreads();
    for (int off = 1; off < 256; off <<= 1) {
        int x = (t >= off) ? s[t - off] : 0;
        __syncthreads();
        s[t] += x;
        __syncthreads();
    }
    int excl = s[t] - tsum;
    if (i0     < NB) { bbase[i0]     = excl; bcur[i0]     = excl; }  excl += v0;
    if (i0 + 1 < NB) { bbase[i0 + 1] = excl; bcur[i0 + 1] = excl; }  excl += v1;
    if (i0 + 2 < NB) { bbase[i0 + 2] = excl; bcur[i0 + 2] = excl; }  excl += v2;
    if (i0 + 3 < NB) { bbase[i0 + 3] = excl; bcur[i0 + 3] = excl; }
    if (t == 255) bbase[NB] = Etot;
}

__global__ __launch_bounds__(256) void pass1_scatter(
    const int* __restrict__ ei, int E, int Etot,
    int* __restrict__ bcur, unsigned* __restrict__ tmp)
{
    int e = blockIdx.x * 256 + threadIdx.x;
    if (e >= Etot) return;
    int src, dst;
    if (e < E) { src = ei[e]; dst = ei[E + e]; }
    else       { src = dst = e - E; }
    int pos = atomicAdd(&bcur[dst >> 7], 1);
    tmp[pos] = ((unsigned)src << 7) | (unsigned)(dst & (BKN - 1));
}

__global__ __launch_bounds__(256) void pass2_sort(
    const unsigned* __restrict__ tmp, const int* __restrict__ bbase,
    int* __restrict__ offs, int* __restrict__ esrc, int n)
{
    __shared__ int cnt[BKN];
    __shared__ int sc[BKN];
    __shared__ int cur[BKN];
    int bk = blockIdx.x;
    int t  = threadIdx.x;
    if (t < BKN) cnt[t] = 0;
    __syncthreads();
    int lo = bbase[bk], hi = bbase[bk + 1];
    for (int i = lo + t; i < hi; i += 256)
        atomicAdd(&cnt[tmp[i] & (BKN - 1)], 1);
    __syncthreads();
    int v = (t < BKN) ? cnt[t] : 0;
    if (t < BKN) sc[t] = v;
    __syncthreads();
    for (int off = 1; off < BKN; off <<= 1) {
        int x = (t < BKN && t >= off) ? sc[t - off] : 0;
        __syncthreads();
        if (t < BKN) sc[t] += x;
        __syncthreads();
    }
    if (t < BKN) {
        int node = bk * BKN + t;
        if (node < n) offs[node] = lo + sc[t];   // inclusive scan -> end(v)
        cur[t] = lo + sc[t] - v;                 // exclusive -> begin cursor
    }
    __syncthreads();
    for (int i = lo + t; i < hi; i += 256) {
        unsigned w = tmp[i];
        int p = atomicAdd(&cur[w & (BKN - 1)], 1);
        esrc[p] = (int)(w >> 7);
    }
}

// ---------------------------------------------------------------------------
// Layer-1 aggregation: one wave per dst node, F=128 (fp16), 4 heads (C=32).
// Lane l handles feature pair (2l, 2l+1) -> head l>>4. Edge loop unrolled x4.
// Fuses softmax normalization + bias + ELU; writes fp32 X2 directly.
// ---------------------------------------------------------------------------
__global__ __launch_bounds__(256) void agg1(
    const int* __restrict__ offs, const int* __restrict__ esrc,
    const __half2* __restrict__ Hh, const float* __restrict__ As,
    const float* __restrict__ Ad, const float* __restrict__ bias,
    float* __restrict__ X2, int n)
{
    int v    = (blockIdx.x * 256 + threadIdx.x) >> 6;
    int lane = threadIdx.x & 63;
    if (v >= n) return;
    int end = offs[v];
    int beg = v ? offs[v - 1] : 0;
    int head = lane >> 4;
    float adv = Ad[(size_t)v * 4 + head];
    float accx = 0.f, accy = 0.f, den = 0.f;
    int j = beg;
    for (; j + 3 < end; j += 4) {
        int s0 = esrc[j], s1 = esrc[j+1], s2 = esrc[j+2], s3 = esrc[j+3];
        float e0 = As[(size_t)s0*4 + head] + adv;
        float e1 = As[(size_t)s1*4 + head] + adv;
        float e2 = As[(size_t)s2*4 + head] + adv;
        float e3 = As[(size_t)s3*4 + head] + adv;
        __half2 q0 = Hh[(size_t)s0*64 + lane];
        __half2 q1 = Hh[(size_t)s1*64 + lane];
        __half2 q2 = Hh[(size_t)s2*64 + lane];
        __half2 q3 = Hh[(size_t)s3*64 + lane];
        e0 = e0 > 0.f ? e0 : NEG_SLOPE*e0;  float w0 = __expf(e0);
        e1 = e1 > 0.f ? e1 : NEG_SLOPE*e1;  float w1 = __expf(e1);
        e2 = e2 > 0.f ? e2 : NEG_SLOPE*e2;  float w2 = __expf(e2);
        e3 = e3 > 0.f ? e3 : NEG_SLOPE*e3;  float w3 = __expf(e3);
        float2 f0 = __half22float2(q0);
        float2 f1 = __half22float2(q1);
        float2 f2 = __half22float2(q2);
        float2 f3 = __half22float2(q3);
        accx += w0*f0.x + w1*f1.x + w2*f2.x + w3*f3.x;
        accy += w0*f0.y + w1*f1.y + w2*f2.y + w3*f3.y;
        den  += w0 + w1 + w2 + w3;
    }
    for (; j < end; ++j) {
        int s = esrc[j];
        float e = As[(size_t)s*4 + head] + adv;
        e = e > 0.f ? e : NEG_SLOPE*e;
        float w = __expf(e);
        float2 f = __half22float2(Hh[(size_t)s*64 + lane]);
        accx += w*f.x; accy += w*f.y; den += w;
    }
    float inv = 1.f / (den + 1e-16f);
    float2 b = ((const float2*)bias)[lane];
    float ox = accx*inv + b.x, oy = accy*inv + b.y;
    ox = ox > 0.f ? ox : __expf(ox) - 1.f;     // ELU
    oy = oy > 0.f ? oy : __expf(oy) - 1.f;
    ((float2*)(X2 + (size_t)v * 128))[lane] = make_float2(ox, oy);
}

// ---------------------------------------------------------------------------
// Layer-2 aggregation: one wave per dst node, F=64 (fp16), 1 head.
// Half-wave 0 takes even edges, half-wave 1 odd edges (32 lanes cover the
// 32 half2 feature pairs); shuffle-combine at the end. Writes d_out (fp32).
// ---------------------------------------------------------------------------
__global__ __launch_bounds__(256) void agg2(
    const int* __restrict__ offs, const int* __restrict__ esrc,
    const __half2* __restrict__ Hh, const float* __restrict__ As,
    const float* __restrict__ Ad, const float* __restrict__ bias,
    float* __restrict__ out, int n)
{
    int v    = (blockIdx.x * 256 + threadIdx.x) >> 6;
    int lane = threadIdx.x & 63;
    if (v >= n) return;
    int half = lane >> 5;
    int li   = lane & 31;
    int end = offs[v];
    int beg = v ? offs[v - 1] : 0;
    float adv = Ad[v];
    float accx = 0.f, accy = 0.f, den = 0.f;
    int j = beg + half;
    for (; j + 2 < end; j += 4) {          // this half's edges, unrolled x2
        int s0 = esrc[j], s1 = esrc[j+2];
        float e0 = As[s0] + adv;
        float e1 = As[s1] + adv;
        __half2 q0 = Hh[(size_t)s0*32 + li];
        __half2 q1 = Hh[(size_t)s1*32 + li];
        e0 = e0 > 0.f ? e0 : NEG_SLOPE*e0;  float w0 = __expf(e0);
        e1 = e1 > 0.f ? e1 : NEG_SLOPE*e1;  float w1 = __expf(e1);
        float2 f0 = __half22float2(q0);
        float2 f1 = __half22float2(q1);
        accx += w0*f0.x + w1*f1.x;
        accy += w0*f0.y + w1*f1.y;
        den  += w0 + w1;
    }
    for (; j < end; j += 2) {
        int s = esrc[j];
        float e = As[s] + adv;
        e = e > 0.f ? e : NEG_SLOPE*e;
        float w = __expf(e);
        float2 f = __half22float2(Hh[(size_t)s*32 + li]);
        accx += w*f.x; accy += w*f.y; den += w;
    }
    accx += __shfl_xor(accx, 32);
    accy += __shfl_xor(accy, 32);
    den  += __shfl_xor(den, 32);
    if (half == 0) {
        float inv = 1.f / (den + 1e-16f);
        float2 b = ((const float2*)bias)[li];
        ((float2*)(out + (size_t)v * 64))[li] =
            make_float2(accx*inv + b.x, accy*inv + b.y);
    }
}

extern "C" void kernel_launch(void* const* d_in, const int* in_sizes, int n_in,
                              void* d_out, int out_size, void* d_ws, size_t ws_size,
                              hipStream_t stream)
{
    (void)n_in; (void)out_size; (void)ws_size;
    const float* x   = (const float*)d_in[0];
    const int*   ei  = (const int*)  d_in[1];
    const float* W1  = (const float*)d_in[2];
    const float* as1 = (const float*)d_in[3];
    const float* ad1 = (const float*)d_in[4];
    const float* b1  = (const float*)d_in[5];
    const float* W2  = (const float*)d_in[6];
    const float* as2 = (const float*)d_in[7];
    const float* ad2 = (const float*)d_in[8];
    const float* b2  = (const float*)d_in[9];
    float* out = (float*)d_out;

    const int n    = in_sizes[0] / 128;   // 100000
    const int E    = in_sizes[1] / 2;     // 1600000
    const int Etot = E + n;               // + self loops
    const int NB   = (n + BKN - 1) / BKN; // buckets (782)

    // Workspace layout (bytes). Layer-2 buffers overlay consumed layer-1 ones.
    char* p = (char*)d_ws;
    __half* Hh = (__half*)p;  p += (size_t)n * 128 * sizeof(__half);  // 25.6MB (L2: n*64)
    float* X2  = (float*)p;   p += (size_t)n * 128 * sizeof(float);   // 51.2MB
    float* As1 = (float*)p;   p += (size_t)n * 4 * sizeof(float);     // (L2: n)
    float* Ad1 = (float*)p;   p += (size_t)n * 4 * sizeof(float);     // (L2: n)
    int* offs  = (int*)p;     p += (size_t)n * sizeof(int);
    int* esrc  = (int*)p;     p += (size_t)Etot * sizeof(int);
    unsigned* tmp = (unsigned*)p; p += (size_t)Etot * sizeof(unsigned);
    int* bcount = (int*)p;    p += MAXNB * sizeof(int);
    int* bbase  = (int*)p;    p += (MAXNB + 1) * sizeof(int);
    int* bcur   = (int*)p;

    // ---- CSR build (bucketed counting sort; shared by both layers) ----
    hipMemsetAsync(bcount, 0, sizeof(int) * (size_t)NB, stream);
    bucket_hist<<<256, 256, 0, stream>>>(ei, E, Etot, NB, bcount);
    bucket_scan<<<1, 256, 0, stream>>>(bcount, NB, Etot, bbase, bcur);
    pass1_scatter<<<(Etot + 255) / 256, 256, 0, stream>>>(ei, E, Etot, bcur, tmp);
    pass2_sort<<<NB, 256, 0, stream>>>(tmp, bbase, offs, esrc, n);

    // ---- Layer 1 ----
    gemm_att<128, 32, 32><<<(n + 31) / 32, 256, 0, stream>>>(x, W1, as1, ad1, Hh, As1, Ad1, n);
    agg1<<<(n * 64 + 255) / 256, 256, 0, stream>>>(offs, esrc, (const __half2*)Hh, As1, Ad1, b1, X2, n);

    // ---- Layer 2 ----
    gemm_att<64, 64, 64><<<(n + 63) / 64, 256, 0, stream>>>(X2, W2, as2, ad2, Hh, As1, Ad1, n);
    agg2<<<(n * 64 + 255) / 256, 256, 0, stream>>>(offs, esrc, (const __half2*)Hh, As1, Ad1, b2, out, n);
}

// Round 5
// 407.160 us; speedup vs baseline: 2.0390x; 2.0390x over previous
//
#include <hip/hip_runtime.h>
#include <hip/hip_fp16.h>

#define NEG_SLOPE 0.2f
#define BKN 128                 // nodes per bucket (pow2)
#define MAXNB 1024              // supports n <= 131072
#define GRP 256                 // pass1/ghist groups (blocks), private cursors

// ---------------------------------------------------------------------------
// Fused GEMM + attention-logit kernel.
//   H[n, BN]   = fp16( X[n, 128] @ W[128, BN] )     (message payload, fp16)
//   As[n, hd]  = sum_c Hf32[n, hd*C+c] * atts[...]  (logits from fp32 accs)
//   Ad[n, hd]  = sum_c Hf32[n, hd*C+c] * attd[...]
// ---------------------------------------------------------------------------
template<int BN, int BM, int C>
__global__ __launch_bounds__(256) void gemm_att(
    const float* __restrict__ X, const float* __restrict__ W,
    const float* __restrict__ atts, const float* __restrict__ attd,
    __half* __restrict__ H, float* __restrict__ As, float* __restrict__ Ad,
    int n)
{
    constexpr int K  = 128;
    constexpr int CG = BN / 4;          // column groups of 4
    constexpr int RW = C / 4;           // shuffle-reduce width (lanes per head)
    constexpr int HEADS = BN / C;

    __shared__ float Wl[K * BN];
    __shared__ float Xl[K * BM];

    const int t = threadIdx.x;
    for (int i = t; i < K * BN / 4; i += 256)
        ((float4*)Wl)[i] = ((const float4*)W)[i];

    const int cg   = t % CG;
    const int rg   = t / CG;
    const int col0 = cg * 4;
    const int head = col0 / C;
    const float s0 = atts[col0], s1 = atts[col0+1], s2 = atts[col0+2], s3 = atts[col0+3];
    const float d0 = attd[col0], d1 = attd[col0+1], d2 = attd[col0+2], d3 = attd[col0+3];

    const int numTiles = (n + BM - 1) / BM;
    for (int tile = blockIdx.x; tile < numTiles; tile += gridDim.x) {
        const int row0 = tile * BM;
        __syncthreads();
        for (int i = t; i < BM * (K / 4); i += 256) {
            int r = i % BM, k4 = i / BM;
            int row = row0 + r;
            float4 v = make_float4(0.f, 0.f, 0.f, 0.f);
            if (row < n) v = ((const float4*)(X + (size_t)row * K))[k4];
            Xl[(k4*4+0)*BM + r] = v.x;
            Xl[(k4*4+1)*BM + r] = v.y;
            Xl[(k4*4+2)*BM + r] = v.z;
            Xl[(k4*4+3)*BM + r] = v.w;
        }
        __syncthreads();

        float acc[4][4];
        #pragma unroll
        for (int a = 0; a < 4; ++a)
            #pragma unroll
            for (int b = 0; b < 4; ++b) acc[a][b] = 0.f;

        #pragma unroll 8
        for (int k = 0; k < K; ++k) {
            float4 a = ((const float4*)(Xl + k * BM))[rg];
            float4 b = ((const float4*)(Wl + k * BN))[cg];
            acc[0][0] += a.x*b.x; acc[0][1] += a.x*b.y; acc[0][2] += a.x*b.z; acc[0][3] += a.x*b.w;
            acc[1][0] += a.y*b.x; acc[1][1] += a.y*b.y; acc[1][2] += a.y*b.z; acc[1][3] += a.y*b.w;
            acc[2][0] += a.z*b.x; acc[2][1] += a.z*b.y; acc[2][2] += a.z*b.z; acc[2][3] += a.z*b.w;
            acc[3][0] += a.w*b.x; acc[3][1] += a.w*b.y; acc[3][2] += a.w*b.z; acc[3][3] += a.w*b.w;
        }

        #pragma unroll
        for (int ri = 0; ri < 4; ++ri) {
            int row = row0 + rg * 4 + ri;
            bool ok = row < n;
            if (ok) {
                __half2 p0 = __floats2half2_rn(acc[ri][0], acc[ri][1]);
                __half2 p1 = __floats2half2_rn(acc[ri][2], acc[ri][3]);
                uint2 u;
                u.x = *(unsigned*)&p0;
                u.y = *(unsigned*)&p1;
                ((uint2*)(H + (size_t)row * BN))[cg] = u;   // 8B packed store
            }
            float ps = acc[ri][0]*s0 + acc[ri][1]*s1 + acc[ri][2]*s2 + acc[ri][3]*s3;
            float pd = acc[ri][0]*d0 + acc[ri][1]*d1 + acc[ri][2]*d2 + acc[ri][3]*d3;
            #pragma unroll
            for (int off = RW / 2; off > 0; off >>= 1) {
                ps += __shfl_down(ps, off, RW);
                pd += __shfl_down(pd, off, RW);
            }
            if (ok && (cg % RW) == 0) {
                As[(size_t)row * HEADS + head] = ps;
                Ad[(size_t)row * HEADS + head] = pd;
            }
        }
    }
}

// ---------------------------------------------------------------------------
// CSR build, bucketed counting sort with per-group private cursors.
// Bucket k = dst >> 7 (BKN=128 nodes). Group g = one of GRP blocks, each
// owning a contiguous edge chunk. cnt[k*GRP+g] = #edges of bucket k in
// group g. After exclusive scan, S[k*GRP+g] is that (bucket,group)
// sub-region start; bucket k region = [S[k*GRP], S[(k+1)*GRP]).
//  ghist  : LDS histogram per group, private row store (no global atomics)
//  scan   : hierarchical exclusive scan of cnt (NB*GRP elements)
//  pass1  : LDS cursors, append records (src<<7)|(dst&127) (no global atomics)
//  pass2  : per-bucket LDS counting sort -> esrc + final offs[]
// offs[v] == end(v); beg(v) = (v ? offs[v-1] : 0).
// ---------------------------------------------------------------------------
__global__ __launch_bounds__(256) void ghist(
    const int* __restrict__ ei, int E, int Etot, int NB, int chunk,
    int* __restrict__ cnt)
{
    __shared__ int h[MAXNB];
    int g = blockIdx.x;
    for (int i = threadIdx.x; i < NB; i += 256) h[i] = 0;
    __syncthreads();
    int lo = g * chunk, hi = min(Etot, lo + chunk);
    for (int e = lo + threadIdx.x; e < hi; e += 256) {
        int dst = (e < E) ? ei[E + e] : (e - E);
        atomicAdd(&h[dst >> 7], 1);
    }
    __syncthreads();
    for (int i = threadIdx.x; i < NB; i += 256) cnt[i * GRP + g] = h[i];
}

// hierarchical exclusive scan: blocks of 1024, then sums, then add-back
__global__ __launch_bounds__(256) void scan_blocks(
    int* __restrict__ data, int n, int* __restrict__ bsum)
{
    __shared__ int s[256];
    int t = threadIdx.x;
    int idx = blockIdx.x * 1024 + t * 4;
    int4 v = make_int4(0, 0, 0, 0);
    if (idx + 3 < n)      v = *(const int4*)(data + idx);
    else {
        if (idx     < n) v.x = data[idx];
        if (idx + 1 < n) v.y = data[idx+1];
        if (idx + 2 < n) v.z = data[idx+2];
        if (idx + 3 < n) v.w = data[idx+3];
    }
    int tsum = v.x + v.y + v.z + v.w;
    s[t] = tsum;
    __syncthreads();
    for (int off = 1; off < 256; off <<= 1) {
        int x = (t >= off) ? s[t - off] : 0;
        __syncthreads();
        s[t] += x;
        __syncthreads();
    }
    int excl = s[t] - tsum;
    if (t == 255) bsum[blockIdx.x] = s[255];
    if (idx     < n) data[idx]     = excl;
    if (idx + 1 < n) data[idx + 1] = excl + v.x;
    if (idx + 2 < n) data[idx + 2] = excl + v.x + v.y;
    if (idx + 3 < n) data[idx + 3] = excl + v.x + v.y + v.z;
}

__global__ __launch_bounds__(256) void scan_sums(int* __restrict__ bsum, int nb)
{
    __shared__ int s[256];
    int t = threadIdx.x;
    int v = (t < nb) ? bsum[t] : 0;
    s[t] = v;
    __syncthreads();
    for (int off = 1; off < 256; off <<= 1) {
        int x = (t >= off) ? s[t - off] : 0;
        __syncthreads();
        s[t] += x;
        __syncthreads();
    }
    if (t < nb) bsum[t] = s[t] - v;
}

__global__ __launch_bounds__(256) void scan_add(
    int* __restrict__ data, int n, const int* __restrict__ bsum)
{
    int i = blockIdx.x * 256 + threadIdx.x;
    if (i < n) data[i] += bsum[i >> 10];
}

__global__ __launch_bounds__(256) void pass1_scatter(
    const int* __restrict__ ei, int E, int Etot, int NB, int chunk,
    const int* __restrict__ S, unsigned* __restrict__ tmp)
{
    __shared__ int cur[MAXNB];
    int g = blockIdx.x;
    for (int i = threadIdx.x; i < NB; i += 256) cur[i] = S[i * GRP + g];
    __syncthreads();
    int lo = g * chunk, hi = min(Etot, lo + chunk);
    for (int e = lo + threadIdx.x; e < hi; e += 256) {
        int src, dst;
        if (e < E) { src = ei[e]; dst = ei[E + e]; }
        else       { src = dst = e - E; }
        int pos = atomicAdd(&cur[dst >> 7], 1);   // LDS atomic, private row
        tmp[pos] = ((unsigned)src << 7) | (unsigned)(dst & (BKN - 1));
    }
}

__global__ __launch_bounds__(256) void pass2_sort(
    const unsigned* __restrict__ tmp, const int* __restrict__ S,
    int NB, int Etot,
    int* __restrict__ offs, int* __restrict__ esrc, int n)
{
    __shared__ int cnt[BKN];
    __shared__ int sc[BKN];
    __shared__ int cur[BKN];
    int bk = blockIdx.x;
    int t  = threadIdx.x;
    if (t < BKN) cnt[t] = 0;
    __syncthreads();
    int lo = S[bk * GRP];
    int hi = (bk + 1 < NB) ? S[(bk + 1) * GRP] : Etot;
    for (int i = lo + t; i < hi; i += 256)
        atomicAdd(&cnt[tmp[i] & (BKN - 1)], 1);
    __syncthreads();
    int v = (t < BKN) ? cnt[t] : 0;
    if (t < BKN) sc[t] = v;
    __syncthreads();
    for (int off = 1; off < BKN; off <<= 1) {
        int x = (t < BKN && t >= off) ? sc[t - off] : 0;
        __syncthreads();
        if (t < BKN) sc[t] += x;
        __syncthreads();
    }
    if (t < BKN) {
        int node = bk * BKN + t;
        if (node < n) offs[node] = lo + sc[t];   // inclusive scan -> end(v)
        cur[t] = lo + sc[t] - v;                 // exclusive -> begin cursor
    }
    __syncthreads();
    for (int i = lo + t; i < hi; i += 256) {
        unsigned w = tmp[i];
        int p = atomicAdd(&cur[w & (BKN - 1)], 1);
        esrc[p] = (int)(w >> 7);
    }
}

// ---------------------------------------------------------------------------
// Layer-1 aggregation: one wave per dst node, F=128 (fp16), 4 heads (C=32).
// Lane l handles feature pair (2l, 2l+1) -> head l>>4. Edge loop unrolled x4.
// Fuses softmax normalization + bias + ELU; writes fp32 X2 directly.
// ---------------------------------------------------------------------------
__global__ __launch_bounds__(256) void agg1(
    const int* __restrict__ offs, const int* __restrict__ esrc,
    const __half2* __restrict__ Hh, const float* __restrict__ As,
    const float* __restrict__ Ad, const float* __restrict__ bias,
    float* __restrict__ X2, int n)
{
    int v    = (blockIdx.x * 256 + threadIdx.x) >> 6;
    int lane = threadIdx.x & 63;
    if (v >= n) return;
    int end = offs[v];
    int beg = v ? offs[v - 1] : 0;
    int head = lane >> 4;
    float adv = Ad[(size_t)v * 4 + head];
    float accx = 0.f, accy = 0.f, den = 0.f;
    int j = beg;
    for (; j + 3 < end; j += 4) {
        int s0 = esrc[j], s1 = esrc[j+1], s2 = esrc[j+2], s3 = esrc[j+3];
        float e0 = As[(size_t)s0*4 + head] + adv;
        float e1 = As[(size_t)s1*4 + head] + adv;
        float e2 = As[(size_t)s2*4 + head] + adv;
        float e3 = As[(size_t)s3*4 + head] + adv;
        __half2 q0 = Hh[(size_t)s0*64 + lane];
        __half2 q1 = Hh[(size_t)s1*64 + lane];
        __half2 q2 = Hh[(size_t)s2*64 + lane];
        __half2 q3 = Hh[(size_t)s3*64 + lane];
        e0 = e0 > 0.f ? e0 : NEG_SLOPE*e0;  float w0 = __expf(e0);
        e1 = e1 > 0.f ? e1 : NEG_SLOPE*e1;  float w1 = __expf(e1);
        e2 = e2 > 0.f ? e2 : NEG_SLOPE*e2;  float w2 = __expf(e2);
        e3 = e3 > 0.f ? e3 : NEG_SLOPE*e3;  float w3 = __expf(e3);
        float2 f0 = __half22float2(q0);
        float2 f1 = __half22float2(q1);
        float2 f2 = __half22float2(q2);
        float2 f3 = __half22float2(q3);
        accx += w0*f0.x + w1*f1.x + w2*f2.x + w3*f3.x;
        accy += w0*f0.y + w1*f1.y + w2*f2.y + w3*f3.y;
        den  += w0 + w1 + w2 + w3;
    }
    for (; j < end; ++j) {
        int s = esrc[j];
        float e = As[(size_t)s*4 + head] + adv;
        e = e > 0.f ? e : NEG_SLOPE*e;
        float w = __expf(e);
        float2 f = __half22float2(Hh[(size_t)s*64 + lane]);
        accx += w*f.x; accy += w*f.y; den += w;
    }
    float inv = 1.f / (den + 1e-16f);
    float2 b = ((const float2*)bias)[lane];
    float ox = accx*inv + b.x, oy = accy*inv + b.y;
    ox = ox > 0.f ? ox : __expf(ox) - 1.f;     // ELU
    oy = oy > 0.f ? oy : __expf(oy) - 1.f;
    ((float2*)(X2 + (size_t)v * 128))[lane] = make_float2(ox, oy);
}

// ---------------------------------------------------------------------------
// Layer-2 aggregation: one wave per dst node, F=64 (fp16), 1 head.
// Half-wave 0 takes even edges, half-wave 1 odd edges (32 lanes cover the
// 32 half2 feature pairs); shuffle-combine at the end. Writes d_out (fp32).
// ---------------------------------------------------------------------------
__global__ __launch_bounds__(256) void agg2(
    const int* __restrict__ offs, const int* __restrict__ esrc,
    const __half2* __restrict__ Hh, const float* __restrict__ As,
    const float* __restrict__ Ad, const float* __restrict__ bias,
    float* __restrict__ out, int n)
{
    int v    = (blockIdx.x * 256 + threadIdx.x) >> 6;
    int lane = threadIdx.x & 63;
    if (v >= n) return;
    int half = lane >> 5;
    int li   = lane & 31;
    int end = offs[v];
    int beg = v ? offs[v - 1] : 0;
    float adv = Ad[v];
    float accx = 0.f, accy = 0.f, den = 0.f;
    int j = beg + half;
    for (; j + 2 < end; j += 4) {          // this half's edges, unrolled x2
        int s0 = esrc[j], s1 = esrc[j+2];
        float e0 = As[s0] + adv;
        float e1 = As[s1] + adv;
        __half2 q0 = Hh[(size_t)s0*32 + li];
        __half2 q1 = Hh[(size_t)s1*32 + li];
        e0 = e0 > 0.f ? e0 : NEG_SLOPE*e0;  float w0 = __expf(e0);
        e1 = e1 > 0.f ? e1 : NEG_SLOPE*e1;  float w1 = __expf(e1);
        float2 f0 = __half22float2(q0);
        float2 f1 = __half22float2(q1);
        accx += w0*f0.x + w1*f1.x;
        accy += w0*f0.y + w1*f1.y;
        den  += w0 + w1;
    }
    for (; j < end; j += 2) {
        int s = esrc[j];
        float e = As[s] + adv;
        e = e > 0.f ? e : NEG_SLOPE*e;
        float w = __expf(e);
        float2 f = __half22float2(Hh[(size_t)s*32 + li]);
        accx += w*f.x; accy += w*f.y; den += w;
    }
    accx += __shfl_xor(accx, 32);
    accy += __shfl_xor(accy, 32);
    den  += __shfl_xor(den, 32);
    if (half == 0) {
        float inv = 1.f / (den + 1e-16f);
        float2 b = ((const float2*)bias)[li];
        ((float2*)(out + (size_t)v * 64))[li] =
            make_float2(accx*inv + b.x, accy*inv + b.y);
    }
}

extern "C" void kernel_launch(void* const* d_in, const int* in_sizes, int n_in,
                              void* d_out, int out_size, void* d_ws, size_t ws_size,
                              hipStream_t stream)
{
    (void)n_in; (void)out_size; (void)ws_size;
    const float* x   = (const float*)d_in[0];
    const int*   ei  = (const int*)  d_in[1];
    const float* W1  = (const float*)d_in[2];
    const float* as1 = (const float*)d_in[3];
    const float* ad1 = (const float*)d_in[4];
    const float* b1  = (const float*)d_in[5];
    const float* W2  = (const float*)d_in[6];
    const float* as2 = (const float*)d_in[7];
    const float* ad2 = (const float*)d_in[8];
    const float* b2  = (const float*)d_in[9];
    float* out = (float*)d_out;

    const int n    = in_sizes[0] / 128;   // 100000
    const int E    = in_sizes[1] / 2;     // 1600000
    const int Etot = E + n;               // + self loops
    const int NB   = (n + BKN - 1) / BKN; // buckets (782)
    const int chunk = (Etot + GRP - 1) / GRP;

    // Workspace layout (bytes). Layer-2 buffers overlay consumed layer-1 ones.
    char* p = (char*)d_ws;
    __half* Hh = (__half*)p;  p += (size_t)n * 128 * sizeof(__half);  // 25.6MB (L2: n*64)
    float* X2  = (float*)p;   p += (size_t)n * 128 * sizeof(float);   // 51.2MB
    float* As1 = (float*)p;   p += (size_t)n * 4 * sizeof(float);     // (L2: n)
    float* Ad1 = (float*)p;   p += (size_t)n * 4 * sizeof(float);     // (L2: n)
    int* offs  = (int*)p;     p += (size_t)n * sizeof(int);
    int* esrc  = (int*)p;     p += (size_t)Etot * sizeof(int);
    unsigned* tmp = (unsigned*)p; p += (size_t)Etot * sizeof(unsigned);
    int* cnt   = (int*)p;     p += (size_t)NB * GRP * sizeof(int);    // 0.8MB
    int* bsum  = (int*)p;     p += 256 * sizeof(int);

    const int scan_n  = NB * GRP;
    const int scan_nb = (scan_n + 1023) / 1024;   // <=256

    // ---- CSR build (contention-free bucketed counting sort) ----
    ghist<<<GRP, 256, 0, stream>>>(ei, E, Etot, NB, chunk, cnt);
    scan_blocks<<<scan_nb, 256, 0, stream>>>(cnt, scan_n, bsum);
    scan_sums<<<1, 256, 0, stream>>>(bsum, scan_nb);
    scan_add<<<(scan_n + 255) / 256, 256, 0, stream>>>(cnt, scan_n, bsum);
    pass1_scatter<<<GRP, 256, 0, stream>>>(ei, E, Etot, NB, chunk, cnt, tmp);
    pass2_sort<<<NB, 256, 0, stream>>>(tmp, cnt, NB, Etot, offs, esrc, n);

    // ---- Layer 1 ----
    gemm_att<128, 32, 32><<<(n + 31) / 32, 256, 0, stream>>>(x, W1, as1, ad1, Hh, As1, Ad1, n);
    agg1<<<(n * 64 + 255) / 256, 256, 0, stream>>>(offs, esrc, (const __half2*)Hh, As1, Ad1, b1, X2, n);

    // ---- Layer 2 ----
    gemm_att<64, 64, 64><<<(n + 63) / 64, 256, 0, stream>>>(X2, W2, as2, ad2, Hh, As1, Ad1, n);
    agg2<<<(n * 64 + 255) / 256, 256, 0, stream>>>(offs, esrc, (const __half2*)Hh, As1, Ad1, b2, out, n);
}

// Round 6
// 339.839 us; speedup vs baseline: 2.4429x; 1.1981x over previous
//
#include <hip/hip_runtime.h>
#include <hip/hip_fp16.h>

#define NEG_SLOPE 0.2f
#define BKN 128                 // nodes per bucket (pow2)
#define MAXNB 1024              // supports n <= 131072
#define GRP 256                 // pass1/ghist groups (blocks), private cursors

typedef _Float16 half_t;
typedef __attribute__((ext_vector_type(8))) _Float16 half8;
typedef __attribute__((ext_vector_type(4))) float floatx4;

// ---------------------------------------------------------------------------
// Weight transpose + fp16 convert: Wt[n][k] = (fp16) W[k][n].  K=128 fixed.
// ---------------------------------------------------------------------------
__global__ __launch_bounds__(256) void w_convert(
    const float* __restrict__ W, half_t* __restrict__ Wt, int N)
{
    int i = blockIdx.x * 256 + threadIdx.x;      // i indexes W row-major (K*N)
    if (i >= 128 * N) return;
    int k = i / N, nn = i % N;
    Wt[nn * 128 + k] = (half_t)W[i];
}

// ---------------------------------------------------------------------------
// MFMA GEMM + fused attention logits.
//   H[n, BN]  = fp16( X[n,128] @ W[128,BN] )    (W given as Wt[BN][128] fp16)
//   As/Ad[n,h] = per-head dot of H row with atts/attd   (fp32)
// Block = 256 thr = 4 waves; M-tile 64 (16 rows/wave); mfma 16x16x32 f16.
// LDS chunk swizzle: 8-half chunk cid stored at cid ^ (row & 15) to avoid
// bank conflicts on row-strided ds_read_b128 (2-way max, free).
// Layouts (verified, cdna4 guide §3): A[m=lane&15][k=quad*8+j],
// B[nn=lane&15][k=quad*8+j], D col=lane&15, row=quad*4+reg.
// ---------------------------------------------------------------------------
template<int BN, int HEADS>
__global__ __launch_bounds__(256) void gemm_mfma(
    const float* __restrict__ X, const half_t* __restrict__ Wt,
    const float* __restrict__ atts, const float* __restrict__ attd,
    half_t* __restrict__ H, float* __restrict__ As, float* __restrict__ Ad,
    int n)
{
    constexpr int K  = 128;
    constexpr int NT = BN / 16;           // col tiles
    constexpr int TPH = NT / HEADS;       // col tiles per head

    __shared__ half_t Wl[BN * K];
    __shared__ half_t Xl[64 * K];

    const int t = threadIdx.x;
    const int wave = t >> 6, lane = t & 63;
    const int quad = lane >> 4, c = lane & 15;

    // att coefficients for this lane's columns (col = nt*16 + c)
    float att_s[NT], att_d[NT];
    #pragma unroll
    for (int nt = 0; nt < NT; ++nt) {
        att_s[nt] = atts[nt * 16 + c];
        att_d[nt] = attd[nt * 16 + c];
    }

    // stage Wt whole (swizzled), once per block
    for (int i = t; i < BN * 16; i += 256) {
        int row = i >> 4, cid = i & 15;
        half8 v = *(const half8*)(Wt + row * K + cid * 8);
        *(half8*)(Wl + row * K + ((cid ^ (row & 15)) << 3)) = v;
    }

    const int numTiles = (n + 63) / 64;
    for (int tile = blockIdx.x; tile < numTiles; tile += gridDim.x) {
        const int row0 = tile * 64;
        __syncthreads();
        // stage X tile: 64 rows x 128 fp32 -> fp16, swizzled. 1024 chunks.
        for (int i = t; i < 1024; i += 256) {
            int m = i >> 4, cid = i & 15;
            int row = row0 + m;
            float4 a = make_float4(0.f,0.f,0.f,0.f), b = a;
            if (row < n) {
                const float4* src = (const float4*)(X + (size_t)row * K + cid * 8);
                a = src[0]; b = src[1];
            }
            half8 h;
            h[0]=(half_t)a.x; h[1]=(half_t)a.y; h[2]=(half_t)a.z; h[3]=(half_t)a.w;
            h[4]=(half_t)b.x; h[5]=(half_t)b.y; h[6]=(half_t)b.z; h[7]=(half_t)b.w;
            *(half8*)(Xl + m * K + ((cid ^ (m & 15)) << 3)) = h;
        }
        __syncthreads();

        floatx4 acc[NT];
        #pragma unroll
        for (int i = 0; i < NT; ++i) acc[i] = (floatx4)(0.f);

        #pragma unroll
        for (int kc = 0; kc < 4; ++kc) {
            int cid = kc * 4 + quad;
            half8 afrag = *(const half8*)(Xl + (wave * 16 + c) * K + ((cid ^ c) << 3));
            #pragma unroll
            for (int nt = 0; nt < NT; ++nt) {
                // B row = nt*16 + c, (row & 15) == c
                half8 bfrag = *(const half8*)(Wl + (nt * 16 + c) * K + ((cid ^ c) << 3));
                acc[nt] = __builtin_amdgcn_mfma_f32_16x16x32_f16(afrag, bfrag, acc[nt], 0, 0, 0);
            }
        }

        // epilogue: rows r = quad*4+reg within wave tile
        #pragma unroll
        for (int reg = 0; reg < 4; ++reg) {
            int row = row0 + wave * 16 + quad * 4 + reg;
            bool ok = row < n;
            if (ok) {
                #pragma unroll
                for (int nt = 0; nt < NT; ++nt)
                    H[(size_t)row * BN + nt * 16 + c] = (half_t)acc[nt][reg];
            }
            #pragma unroll
            for (int h = 0; h < HEADS; ++h) {
                float ps = 0.f, pd = 0.f;
                #pragma unroll
                for (int u = 0; u < TPH; ++u) {
                    int nt = h * TPH + u;
                    ps += acc[nt][reg] * att_s[nt];
                    pd += acc[nt][reg] * att_d[nt];
                }
                #pragma unroll
                for (int off = 1; off < 16; off <<= 1) {
                    ps += __shfl_xor(ps, off);
                    pd += __shfl_xor(pd, off);
                }
                if (ok && c == 0) {
                    As[(size_t)row * HEADS + h] = ps;
                    Ad[(size_t)row * HEADS + h] = pd;
                }
            }
        }
    }
}

// ---------------------------------------------------------------------------
// CSR build, bucketed counting sort with per-group private cursors.
// (contention-free: LDS atomics on private rows, zero global atomics)
// ---------------------------------------------------------------------------
__global__ __launch_bounds__(256) void ghist(
    const int* __restrict__ ei, int E, int Etot, int NB, int chunk,
    int* __restrict__ cnt)
{
    __shared__ int h[MAXNB];
    int g = blockIdx.x;
    for (int i = threadIdx.x; i < NB; i += 256) h[i] = 0;
    __syncthreads();
    int lo = g * chunk, hi = min(Etot, lo + chunk);
    for (int e = lo + threadIdx.x; e < hi; e += 256) {
        int dst = (e < E) ? ei[E + e] : (e - E);
        atomicAdd(&h[dst >> 7], 1);
    }
    __syncthreads();
    for (int i = threadIdx.x; i < NB; i += 256) cnt[i * GRP + g] = h[i];
}

__global__ __launch_bounds__(256) void scan_blocks(
    int* __restrict__ data, int n, int* __restrict__ bsum)
{
    __shared__ int s[256];
    int t = threadIdx.x;
    int idx = blockIdx.x * 1024 + t * 4;
    int4 v = make_int4(0, 0, 0, 0);
    if (idx + 3 < n)      v = *(const int4*)(data + idx);
    else {
        if (idx     < n) v.x = data[idx];
        if (idx + 1 < n) v.y = data[idx+1];
        if (idx + 2 < n) v.z = data[idx+2];
        if (idx + 3 < n) v.w = data[idx+3];
    }
    int tsum = v.x + v.y + v.z + v.w;
    s[t] = tsum;
    __syncthreads();
    for (int off = 1; off < 256; off <<= 1) {
        int x = (t >= off) ? s[t - off] : 0;
        __syncthreads();
        s[t] += x;
        __syncthreads();
    }
    int excl = s[t] - tsum;
    if (t == 255) bsum[blockIdx.x] = s[255];
    if (idx     < n) data[idx]     = excl;
    if (idx + 1 < n) data[idx + 1] = excl + v.x;
    if (idx + 2 < n) data[idx + 2] = excl + v.x + v.y;
    if (idx + 3 < n) data[idx + 3] = excl + v.x + v.y + v.z;
}

__global__ __launch_bounds__(256) void scan_sums(int* __restrict__ bsum, int nb)
{
    __shared__ int s[256];
    int t = threadIdx.x;
    int v = (t < nb) ? bsum[t] : 0;
    s[t] = v;
    __syncthreads();
    for (int off = 1; off < 256; off <<= 1) {
        int x = (t >= off) ? s[t - off] : 0;
        __syncthreads();
        s[t] += x;
        __syncthreads();
    }
    if (t < nb) bsum[t] = s[t] - v;
}

__global__ __launch_bounds__(256) void scan_add(
    int* __restrict__ data, int n, const int* __restrict__ bsum)
{
    int i = blockIdx.x * 256 + threadIdx.x;
    if (i < n) data[i] += bsum[i >> 10];
}

__global__ __launch_bounds__(256) void pass1_scatter(
    const int* __restrict__ ei, int E, int Etot, int NB, int chunk,
    const int* __restrict__ S, unsigned* __restrict__ tmp)
{
    __shared__ int cur[MAXNB];
    int g = blockIdx.x;
    for (int i = threadIdx.x; i < NB; i += 256) cur[i] = S[i * GRP + g];
    __syncthreads();
    int lo = g * chunk, hi = min(Etot, lo + chunk);
    for (int e = lo + threadIdx.x; e < hi; e += 256) {
        int src, dst;
        if (e < E) { src = ei[e]; dst = ei[E + e]; }
        else       { src = dst = e - E; }
        int pos = atomicAdd(&cur[dst >> 7], 1);   // LDS atomic, private row
        tmp[pos] = ((unsigned)src << 7) | (unsigned)(dst & (BKN - 1));
    }
}

__global__ __launch_bounds__(256) void pass2_sort(
    const unsigned* __restrict__ tmp, const int* __restrict__ S,
    int NB, int Etot,
    int* __restrict__ offs, int* __restrict__ esrc, int n)
{
    __shared__ int cnt[BKN];
    __shared__ int sc[BKN];
    __shared__ int cur[BKN];
    int bk = blockIdx.x;
    int t  = threadIdx.x;
    if (t < BKN) cnt[t] = 0;
    __syncthreads();
    int lo = S[bk * GRP];
    int hi = (bk + 1 < NB) ? S[(bk + 1) * GRP] : Etot;
    for (int i = lo + t; i < hi; i += 256)
        atomicAdd(&cnt[tmp[i] & (BKN - 1)], 1);
    __syncthreads();
    int v = (t < BKN) ? cnt[t] : 0;
    if (t < BKN) sc[t] = v;
    __syncthreads();
    for (int off = 1; off < BKN; off <<= 1) {
        int x = (t < BKN && t >= off) ? sc[t - off] : 0;
        __syncthreads();
        if (t < BKN) sc[t] += x;
        __syncthreads();
    }
    if (t < BKN) {
        int node = bk * BKN + t;
        if (node < n) offs[node] = lo + sc[t];   // inclusive scan -> end(v)
        cur[t] = lo + sc[t] - v;                 // exclusive -> begin cursor
    }
    __syncthreads();
    for (int i = lo + t; i < hi; i += 256) {
        unsigned w = tmp[i];
        int p = atomicAdd(&cur[w & (BKN - 1)], 1);
        esrc[p] = (int)(w >> 7);
    }
}

// ---------------------------------------------------------------------------
// Layer-1 aggregation: one wave per dst node, F=128 (fp16), 4 heads (C=32).
// Lane l handles feature pair (2l, 2l+1) -> head l>>4. Edge loop unrolled x4.
// Fuses softmax normalization + bias + ELU; writes fp32 X2 directly.
// ---------------------------------------------------------------------------
__global__ __launch_bounds__(256) void agg1(
    const int* __restrict__ offs, const int* __restrict__ esrc,
    const __half2* __restrict__ Hh, const float* __restrict__ As,
    const float* __restrict__ Ad, const float* __restrict__ bias,
    float* __restrict__ X2, int n)
{
    int v    = (blockIdx.x * 256 + threadIdx.x) >> 6;
    int lane = threadIdx.x & 63;
    if (v >= n) return;
    int end = offs[v];
    int beg = v ? offs[v - 1] : 0;
    int head = lane >> 4;
    float adv = Ad[(size_t)v * 4 + head];
    float accx = 0.f, accy = 0.f, den = 0.f;
    int j = beg;
    for (; j + 3 < end; j += 4) {
        int s0 = esrc[j], s1 = esrc[j+1], s2 = esrc[j+2], s3 = esrc[j+3];
        float e0 = As[(size_t)s0*4 + head] + adv;
        float e1 = As[(size_t)s1*4 + head] + adv;
        float e2 = As[(size_t)s2*4 + head] + adv;
        float e3 = As[(size_t)s3*4 + head] + adv;
        __half2 q0 = Hh[(size_t)s0*64 + lane];
        __half2 q1 = Hh[(size_t)s1*64 + lane];
        __half2 q2 = Hh[(size_t)s2*64 + lane];
        __half2 q3 = Hh[(size_t)s3*64 + lane];
        e0 = e0 > 0.f ? e0 : NEG_SLOPE*e0;  float w0 = __expf(e0);
        e1 = e1 > 0.f ? e1 : NEG_SLOPE*e1;  float w1 = __expf(e1);
        e2 = e2 > 0.f ? e2 : NEG_SLOPE*e2;  float w2 = __expf(e2);
        e3 = e3 > 0.f ? e3 : NEG_SLOPE*e3;  float w3 = __expf(e3);
        float2 f0 = __half22float2(q0);
        float2 f1 = __half22float2(q1);
        float2 f2 = __half22float2(q2);
        float2 f3 = __half22float2(q3);
        accx += w0*f0.x + w1*f1.x + w2*f2.x + w3*f3.x;
        accy += w0*f0.y + w1*f1.y + w2*f2.y + w3*f3.y;
        den  += w0 + w1 + w2 + w3;
    }
    for (; j < end; ++j) {
        int s = esrc[j];
        float e = As[(size_t)s*4 + head] + adv;
        e = e > 0.f ? e : NEG_SLOPE*e;
        float w = __expf(e);
        float2 f = __half22float2(Hh[(size_t)s*64 + lane]);
        accx += w*f.x; accy += w*f.y; den += w;
    }
    float inv = 1.f / (den + 1e-16f);
    float2 b = ((const float2*)bias)[lane];
    float ox = accx*inv + b.x, oy = accy*inv + b.y;
    ox = ox > 0.f ? ox : __expf(ox) - 1.f;     // ELU
    oy = oy > 0.f ? oy : __expf(oy) - 1.f;
    ((float2*)(X2 + (size_t)v * 128))[lane] = make_float2(ox, oy);
}

// ---------------------------------------------------------------------------
// Layer-2 aggregation: one wave per dst node, F=64 (fp16), 1 head.
// Half-wave h takes edges beg+h, beg+h+2, ...; unrolled x4 (8 edges in
// flight per wave); shuffle-combine at the end. Writes d_out (fp32).
// ---------------------------------------------------------------------------
__global__ __launch_bounds__(256) void agg2(
    const int* __restrict__ offs, const int* __restrict__ esrc,
    const __half2* __restrict__ Hh, const float* __restrict__ As,
    const float* __restrict__ Ad, const float* __restrict__ bias,
    float* __restrict__ out, int n)
{
    int v    = (blockIdx.x * 256 + threadIdx.x) >> 6;
    int lane = threadIdx.x & 63;
    if (v >= n) return;
    int half = lane >> 5;
    int li   = lane & 31;
    int end = offs[v];
    int beg = v ? offs[v - 1] : 0;
    float adv = Ad[v];
    float accx = 0.f, accy = 0.f, den = 0.f;
    int j = beg + half;
    for (; j + 6 < end; j += 8) {          // 4 edges for this half
        int s0 = esrc[j], s1 = esrc[j+2], s2 = esrc[j+4], s3 = esrc[j+6];
        float e0 = As[s0] + adv;
        float e1 = As[s1] + adv;
        float e2 = As[s2] + adv;
        float e3 = As[s3] + adv;
        __half2 q0 = Hh[(size_t)s0*32 + li];
        __half2 q1 = Hh[(size_t)s1*32 + li];
        __half2 q2 = Hh[(size_t)s2*32 + li];
        __half2 q3 = Hh[(size_t)s3*32 + li];
        e0 = e0 > 0.f ? e0 : NEG_SLOPE*e0;  float w0 = __expf(e0);
        e1 = e1 > 0.f ? e1 : NEG_SLOPE*e1;  float w1 = __expf(e1);
        e2 = e2 > 0.f ? e2 : NEG_SLOPE*e2;  float w2 = __expf(e2);
        e3 = e3 > 0.f ? e3 : NEG_SLOPE*e3;  float w3 = __expf(e3);
        float2 f0 = __half22float2(q0);
        float2 f1 = __half22float2(q1);
        float2 f2 = __half22float2(q2);
        float2 f3 = __half22float2(q3);
        accx += w0*f0.x + w1*f1.x + w2*f2.x + w3*f3.x;
        accy += w0*f0.y + w1*f1.y + w2*f2.y + w3*f3.y;
        den  += w0 + w1 + w2 + w3;
    }
    for (; j < end; j += 2) {
        int s = esrc[j];
        float e = As[s] + adv;
        e = e > 0.f ? e : NEG_SLOPE*e;
        float w = __expf(e);
        float2 f = __half22float2(Hh[(size_t)s*32 + li]);
        accx += w*f.x; accy += w*f.y; den += w;
    }
    accx += __shfl_xor(accx, 32);
    accy += __shfl_xor(accy, 32);
    den  += __shfl_xor(den, 32);
    if (half == 0) {
        float inv = 1.f / (den + 1e-16f);
        float2 b = ((const float2*)bias)[li];
        ((float2*)(out + (size_t)v * 64))[li] =
            make_float2(accx*inv + b.x, accy*inv + b.y);
    }
}

extern "C" void kernel_launch(void* const* d_in, const int* in_sizes, int n_in,
                              void* d_out, int out_size, void* d_ws, size_t ws_size,
                              hipStream_t stream)
{
    (void)n_in; (void)out_size; (void)ws_size;
    const float* x   = (const float*)d_in[0];
    const int*   ei  = (const int*)  d_in[1];
    const float* W1  = (const float*)d_in[2];
    const float* as1 = (const float*)d_in[3];
    const float* ad1 = (const float*)d_in[4];
    const float* b1  = (const float*)d_in[5];
    const float* W2  = (const float*)d_in[6];
    const float* as2 = (const float*)d_in[7];
    const float* ad2 = (const float*)d_in[8];
    const float* b2  = (const float*)d_in[9];
    float* out = (float*)d_out;

    const int n    = in_sizes[0] / 128;   // 100000
    const int E    = in_sizes[1] / 2;     // 1600000
    const int Etot = E + n;               // + self loops
    const int NB   = (n + BKN - 1) / BKN; // buckets (782)
    const int chunk = (Etot + GRP - 1) / GRP;

    // Workspace layout (bytes). Layer-2 buffers overlay consumed layer-1 ones.
    char* p = (char*)d_ws;
    half_t* Hh = (half_t*)p;  p += (size_t)n * 128 * sizeof(half_t);  // 25.6MB (L2: n*64)
    float* X2  = (float*)p;   p += (size_t)n * 128 * sizeof(float);   // 51.2MB
    float* As1 = (float*)p;   p += (size_t)n * 4 * sizeof(float);     // (L2: n)
    float* Ad1 = (float*)p;   p += (size_t)n * 4 * sizeof(float);     // (L2: n)
    int* offs  = (int*)p;     p += (size_t)n * sizeof(int);
    int* esrc  = (int*)p;     p += (size_t)Etot * sizeof(int);
    unsigned* tmp = (unsigned*)p; p += (size_t)Etot * sizeof(unsigned);
    int* cnt   = (int*)p;     p += (size_t)NB * GRP * sizeof(int);    // 0.8MB
    int* bsum  = (int*)p;     p += 256 * sizeof(int);
    half_t* Wt1 = (half_t*)p; p += 128 * 128 * sizeof(half_t);        // 32KB
    half_t* Wt2 = (half_t*)p; p += 64 * 128 * sizeof(half_t);         // 16KB

    const int scan_n  = NB * GRP;
    const int scan_nb = (scan_n + 1023) / 1024;   // <=256

    // ---- weight convert (fp32 -> fp16, transposed to [N][K]) ----
    w_convert<<<(128 * 128 + 255) / 256, 256, 0, stream>>>(W1, Wt1, 128);
    w_convert<<<(128 * 64  + 255) / 256, 256, 0, stream>>>(W2, Wt2, 64);

    // ---- CSR build (contention-free bucketed counting sort) ----
    ghist<<<GRP, 256, 0, stream>>>(ei, E, Etot, NB, chunk, cnt);
    scan_blocks<<<scan_nb, 256, 0, stream>>>(cnt, scan_n, bsum);
    scan_sums<<<1, 256, 0, stream>>>(bsum, scan_nb);
    scan_add<<<(scan_n + 255) / 256, 256, 0, stream>>>(cnt, scan_n, bsum);
    pass1_scatter<<<GRP, 256, 0, stream>>>(ei, E, Etot, NB, chunk, cnt, tmp);
    pass2_sort<<<NB, 256, 0, stream>>>(tmp, cnt, NB, Etot, offs, esrc, n);

    const int gtiles = (n + 63) / 64;

    // ---- Layer 1 ----
    gemm_mfma<128, 4><<<gtiles, 256, 0, stream>>>(x, Wt1, as1, ad1, Hh, As1, Ad1, n);
    agg1<<<(n * 64 + 255) / 256, 256, 0, stream>>>(offs, esrc, (const __half2*)Hh, As1, Ad1, b1, X2, n);

    // ---- Layer 2 ----
    gemm_mfma<64, 1><<<gtiles, 256, 0, stream>>>(X2, Wt2, as2, ad2, Hh, As1, Ad1, n);
    agg2<<<(n * 64 + 255) / 256, 256, 0, stream>>>(offs, esrc, (const __half2*)Hh, As1, Ad1, b2, out, n);
}